// Round 5
// baseline (298.004 us; speedup 1.0000x reference)
//
#include <hip/hip_runtime.h>
#include <hip/hip_bf16.h>

#define N_ 64
#define C_ 256
#define T_ 64
#define V_ 25
#define K_ 8
#define VN_ 5
#define VT_ 30
#define CG_ 32
#define H_ 8
#define O_ 256
#define OG_ 32
#define TOPK_ 9

typedef __attribute__((ext_vector_type(8))) short short8;
typedef __attribute__((ext_vector_type(4))) float f32x4;

__device__ __forceinline__ short bfbits(float f) {
    union { __hip_bfloat16 h; short s; } cv;
    cv.h = __float2bfloat16(f);
    return cv.s;
}
__device__ __forceinline__ short8 mk8(f32x4 a, f32x4 b) {
    short8 r;
    r[0] = bfbits(a[0]); r[1] = bfbits(a[1]); r[2] = bfbits(a[2]); r[3] = bfbits(a[3]);
    r[4] = bfbits(b[0]); r[5] = bfbits(b[1]); r[6] = bfbits(b[2]); r[7] = bfbits(b[3]);
    return r;
}
__device__ __forceinline__ short8 mk8f(const float* v) {
    short8 r;
    #pragma unroll
    for (int j = 0; j < 8; ++j) r[j] = bfbits(v[j]);
    return r;
}
__device__ __forceinline__ unsigned pkbf(float a, float b) {
    return (unsigned)(unsigned short)bfbits(a) | ((unsigned)(unsigned short)bfbits(b) << 16);
}

// ---------------- Kernel 1: coalesced T-mean pooling (+ output-tail copy) ----
__global__ __launch_bounds__(256) void k_pool(const float* __restrict__ x,
                                              const float* __restrict__ hyper,
                                              float* __restrict__ pooled,
                                              float* __restrict__ out_tail) {
    __shared__ float ls[6400];
    int b = blockIdx.x;
    int tid = threadIdx.x;
    if (b >= N_ * 64) {   // tail block: hyper passthrough (VN_*C_ = 1280)
        for (int i = tid; i < VN_ * C_; i += 256) out_tail[i] = hyper[i];
        return;
    }
    int n = b >> 6, c0 = (b & 63) * 4;
    const float4* xp = (const float4*)(x + (size_t)(n * C_ + c0) * (T_ * V_));
    for (int i = tid; i < 1600; i += 256) ((float4*)ls)[i] = xp[i];
    __syncthreads();
    if (tid < 100) {
        int c_l = tid / 25, v = tid % 25;
        const float* p = ls + c_l * 1600 + v;
        float s = 0.f;
        #pragma unroll
        for (int t = 0; t < T_; ++t) s += p[t * 25];
        pooled[(size_t)(n * C_ + c0 + c_l) * 25 + v] = s * (1.0f / T_);
    }
}

// ---------------- Kernel 2: graph construction -> adjR[n][k][u][v] (32x32) ---
__global__ __launch_bounds__(256) void k_graph(
    const float* __restrict__ pooled, const float* __restrict__ hyper,
    const float* __restrict__ adjc, const float* __restrict__ edge,
    const float* __restrict__ alpha,
    const float* __restrict__ to_v_w, const float* __restrict__ to_v_b,
    const float* __restrict__ to_w1_w, const float* __restrict__ to_w1_b,
    const float* __restrict__ to_w2_w, const float* __restrict__ to_w2_b,
    float* __restrict__ adjR) {
    __shared__ float smem[12000];
    float* vproj = smem;              // 1920: [k][v][h]
    float* w1s   = smem + 1920;       // 1920: [q][v], q=k*H+h
    float* pg    = smem + 3840;       // 7680: [c][v]  (phase A only)
    float* inc   = smem + 3840;       // 7200: [k][u][v] (phase B, aliases pg)
    float* wt    = smem + 11040;      // 240
    float* gv    = smem + 11280;      // 240
    float* rs    = smem + 11520;      // 240
    float* rsA   = smem + 11760;      // 240

    int n = blockIdx.x;
    int tid = threadIdx.x;
    for (int i = tid; i < C_ * V_; i += 256) {
        int c = i / V_, v = i % V_;
        pg[c * VT_ + v] = pooled[(size_t)n * C_ * V_ + i];
    }
    for (int i = tid; i < C_ * VN_; i += 256) {
        int c = i / VN_, j = i % VN_;
        pg[c * VT_ + V_ + j] = hyper[j * C_ + c];
    }
    __syncthreads();

    for (int i = tid; i < K_ * VT_ * H_; i += 256) {
        int k = i / (VT_ * H_);
        int r = i % (VT_ * H_);
        int v = r / H_, h = r % H_;
        const float* w = to_v_w + (k * H_ + h) * CG_;
        const float* pgk = pg + (k * CG_) * VT_ + v;
        float s = 0.f;
        #pragma unroll
        for (int c = 0; c < CG_; ++c) s += pgk[c * VT_] * w[c];
        vproj[(k * VT_ + v) * H_ + h] = s + to_v_b[k * H_ + h];
    }
    for (int i = tid; i < K_ * H_ * VT_; i += 256) {
        int k = i / (H_ * VT_);
        int r = i % (H_ * VT_);
        int h = r / VT_, v = r % VT_;
        const float* w = to_w1_w + (k * H_ + h) * CG_;
        const float* pgk = pg + (k * CG_) * VT_ + v;
        float s = 0.f;
        #pragma unroll
        for (int c = 0; c < CG_; ++c) s += pgk[c * VT_] * w[c];
        s += to_w1_b[k * H_ + h];
        w1s[(k * H_ + h) * VT_ + v] = (s > 0.f) ? s : 0.01f * s;  // leaky_relu
    }
    __syncthreads();   // pg dead after this barrier

    if (tid < K_ * VT_) {
        int k = tid / VT_;
        float s = to_w2_b[k];
        #pragma unroll
        for (int q = 0; q < K_ * H_; ++q)
            s += w1s[q * VT_ + (tid % VT_)] * to_w2_w[k * K_ * H_ + q];
        wt[tid] = tanhf(s);
        float sa = 0.f;
        const float* ea = edge + (size_t)tid * VT_;
        const float* aa = adjc + (size_t)tid * VT_;
        #pragma unroll
        for (int w2 = 0; w2 < VT_; ++w2) sa += fabsf(ea[w2] * aa[w2]);
        rsA[tid] = sa + 1e-8f;
    }
    if (tid < K_ * VT_) {
        int k = tid / VT_, u = tid % VT_;
        const float* vu = vproj + (k * VT_ + u) * H_;
        float nd[VT_];
        #pragma unroll
        for (int v = 0; v < VT_; ++v) {
            const float* vv = vproj + (k * VT_ + v) * H_;
            float d2 = 0.f;
            #pragma unroll
            for (int h = 0; h < H_; ++h) { float df = vu[h] - vv[h]; d2 += df * df; }
            nd[v] = (d2 > 0.f) ? -sqrtf(d2) : 0.0f;   // -dist
        }
        unsigned taken = 0;
        float vals[TOPK_]; int ids[TOPK_];
        for (int j = 0; j < TOPK_; ++j) {
            float best = -3.4e38f; int bi = 0;
            #pragma unroll
            for (int v = 0; v < VT_; ++v) {
                if (!((taken >> v) & 1u) && nd[v] > best) { best = nd[v]; bi = v; }
            }
            vals[j] = best; ids[j] = bi; taken |= (1u << bi);
        }
        float m = vals[0], se = 0.f, e[TOPK_];
        #pragma unroll
        for (int j = 0; j < TOPK_; ++j) { e[j] = expf(vals[j] - m); se += e[j]; }
        float invse = 1.f / se;
        float* row = inc + (size_t)tid * VT_;
        #pragma unroll
        for (int v = 0; v < VT_; ++v) row[v] = 0.f;
        for (int j = 0; j < TOPK_; ++j) row[ids[j]] = e[j] * invse;
    }
    __syncthreads();

    if (tid < K_ * VT_) {
        int k = tid / VT_, v = tid % VT_;
        float cs = 0.f;
        #pragma unroll
        for (int u = 0; u < VT_; ++u) cs += fabsf(inc[(k * VT_ + u) * VT_ + v]);
        float d = wt[tid] / (cs + 1e-8f);
        gv[tid] = wt[tid] * d;
        float s = 0.f;
        const float* row = inc + (size_t)tid * VT_;
        const float* w = wt + k * VT_;
        #pragma unroll
        for (int vv = 0; vv < VT_; ++vv) s += fabsf(row[vv] * w[vv]);
        rs[tid] = s + 1e-8f;
    }
    __syncthreads();

    // adjR[u][v] = adj_norm + relu(alpha)*hyper_adj, padded to 32x32 with zeros.
    float ar = alpha[0]; ar = ar > 0.f ? ar : 0.f;
    int kk = tid >> 5, uu = tid & 31;
    size_t obase = (size_t)n * K_ * 1024 + (size_t)kk * 1024 + (size_t)uu * 32;
    if (uu < VT_) {
        const float* ru = inc + (kk * VT_ + uu) * VT_;
        const float* g  = gv + kk * VT_;
        float tu[VT_];
        #pragma unroll
        for (int vv = 0; vv < VT_; ++vv) tu[vv] = ru[vv] * g[vv];
        float inv_rs = 1.0f / rs[kk * VT_ + uu];
        float inv_rsA = 1.0f / rsA[kk * VT_ + uu];
        for (int v = 0; v < 32; ++v) {
            float val = 0.f;
            if (v < VT_) {
                const float* rw = inc + (kk * VT_ + v) * VT_;
                float s = 0.f;
                #pragma unroll
                for (int vv = 0; vv < VT_; ++vv) s += tu[vv] * rw[vv];
                int ei = (kk * VT_ + uu) * VT_ + v;
                val = edge[ei] * adjc[ei] * inv_rsA + ar * (s * inv_rs);
            }
            adjR[obase + v] = val;
        }
    } else {
        #pragma unroll
        for (int v = 0; v < 32; ++v) adjR[obase + v] = 0.f;
    }
}

// ---------------- Kernel 3: row-contiguous LDS tile, b128 stage/writeback ----
// Block (n,k,tc): stage x[32c][4t*25v] -> xs[c][132] (100 used) as pure f32x4
// copies (no element scatter). Wave w owns t-window [w*25, w*25+25):
//   GEMM-M: M[c][u] = sum_v xv[c][v]*adjR[u][v]   (A: 8 scalar ds_reads, imm offs)
//   M -> per-wave LDS Mb packed bf16 (row u: 18 dwords)
//   GEMM-Y: Y[o][u] = sum_c W[o][c]*M[c][u] (+ cb[o]*S[u])
//   Epilogue in place at xs[c][w*25+u] (disjoint per-wave windows).
// Barrier + f32x4 nontemporal writeback (exact inverse of staging).
__global__ __launch_bounds__(256, 6) void k_main(
    const float* __restrict__ x, const float* __restrict__ hyper,
    const float* __restrict__ adjR,
    const float* __restrict__ conv_w, const float* __restrict__ conv_b,
    const float* __restrict__ gamma, const float* __restrict__ beta,
    float* __restrict__ out) {
    __shared__ __align__(16) float xs[32 * 132];        // [c][132], 100 used
    __shared__ __align__(16) unsigned Mb[4 * 32 * 18];  // per-wave [u][18]

    int b = blockIdx.x;
    int tc = b & 15, k = (b >> 4) & 7, n = b >> 7;
    int tid = threadIdx.x;
    int w = tid >> 6;
    int lane = tid & 63;
    int qd = lane >> 4;        // quad 0..3
    int l16 = lane & 15;

    // ---- stage x slice (32c x 100 floats) coalesced: 800 f32x4 copies ----
    const float* xg = x + ((size_t)(n * C_ + k * CG_) * T_ + tc * 4) * V_;
    #pragma unroll
    for (int ii = 0; ii < 4; ++ii) {
        int i = tid + ii * 256;
        if (i < 800) {
            int c = i / 25, col = i % 25;
            f32x4 f4 = *(const f32x4*)(xg + (size_t)c * (T_ * V_) + col * 4);
            *(f32x4*)(xs + c * 132 + col * 4) = f4;
        }
    }

    // ---- block-constant register fragments (issued while staging in flight) --
    short8 Wf[2];   // W[o=16mi+l16][c=qd*8+j]
    #pragma unroll
    for (int mi = 0; mi < 2; ++mi) {
        const float* wp = conv_w + (size_t)(k * OG_ + 16 * mi + l16) * CG_ + qd * 8;
        Wf[mi] = mk8(*(const f32x4*)wp, *(const f32x4*)(wp + 4));
    }
    short8 Bf[2]; float Su[2];   // adjR[u=16ni+l16][v=qd*8+j]; f32 row sums S[u]
    #pragma unroll
    for (int ni = 0; ni < 2; ++ni) {
        const float* ap = adjR + (((size_t)(n * K_ + k)) * 32 + 16 * ni + l16) * 32 + qd * 8;
        f32x4 a0 = *(const f32x4*)ap, a1 = *(const f32x4*)(ap + 4);
        Bf[ni] = mk8(a0, a1);
        float s = a0[0] + a0[1] + a0[2] + a0[3] + a1[0] + a1[1] + a1[2] + a1[3];
        s += __shfl_xor(s, 16);
        s += __shfl_xor(s, 32);
        Su[ni] = s;
    }
    f32x4 cb4[2], sc4[2], bt4[2];   // per o-quad: o = 16mi + qd*4 + r
    #pragma unroll
    for (int mi = 0; mi < 2; ++mi) {
        int o0 = k * OG_ + 16 * mi + qd * 4;
        cb4[mi] = *(const f32x4*)(conv_b + o0);
        f32x4 g = *(const f32x4*)(gamma + o0);
        #pragma unroll
        for (int r = 0; r < 4; ++r) g[r] *= 0.999995000037f;  // 1/sqrt(1+1e-5)
        sc4[mi] = g;
        bt4[mi] = *(const f32x4*)(beta + o0);
    }
    short8 Ht[2];   // qd==3 A-template: slot0=x[..][24] (per t), 1..5=hyper, 6,7=0
    #pragma unroll
    for (int mi = 0; mi < 2; ++mi) {
        int c = k * CG_ + 16 * mi + l16;
        short8 h;
        h[0] = 0; h[6] = 0; h[7] = 0;
        #pragma unroll
        for (int j = 0; j < 5; ++j) h[1 + j] = bfbits(hyper[j * C_ + c]);
        Ht[mi] = h;
    }

    __syncthreads();

    unsigned* Mbw = Mb + w * (32 * 18);

    // A-frags: xv[c=16mi+l16][v=qd*8+j] at xs[c*132 + w*25 + v]
    short8 Ax[2];
    #pragma unroll
    for (int mi = 0; mi < 2; ++mi) {
        const float* xp = xs + (16 * mi + l16) * 132 + w * 25;
        if (qd < 3) {
            float va[8];
            #pragma unroll
            for (int j = 0; j < 8; ++j) va[j] = xp[qd * 8 + j];
            Ax[mi] = mk8f(va);
        } else {
            short8 h = Ht[mi];
            h[0] = bfbits(xp[24]);
            Ax[mi] = h;
        }
    }
    // GEMM-M: lane(qd,l16) gets M[c=16mi+qd*4+r][u=16ni+l16]
    f32x4 CM[2][2];
    #pragma unroll
    for (int mi = 0; mi < 2; ++mi)
        #pragma unroll
        for (int ni = 0; ni < 2; ++ni) {
            f32x4 z = {0.f, 0.f, 0.f, 0.f};
            CM[mi][ni] = __builtin_amdgcn_mfma_f32_16x16x32_bf16(Ax[mi], Bf[ni], z, 0, 0, 0);
        }
    // M -> Mb packed bf16: row u, dword d = 8mi + 2qd + {0,1} holds c {2d,2d+1}
    #pragma unroll
    for (int mi = 0; mi < 2; ++mi)
        #pragma unroll
        for (int ni = 0; ni < 2; ++ni) {
            int u = 16 * ni + l16;
            uint2 pr;
            pr.x = pkbf(CM[mi][ni][0], CM[mi][ni][1]);
            pr.y = pkbf(CM[mi][ni][2], CM[mi][ni][3]);
            *(uint2*)(Mbw + u * 18 + 8 * mi + 2 * qd) = pr;
        }
    // B-frags of GEMM-Y: M[u=16ni+l16][c=qd*8+j] -> dwords qd*4..qd*4+3
    short8 Bm[2];
    #pragma unroll
    for (int ni = 0; ni < 2; ++ni) {
        int u = 16 * ni + l16;
        uint2 lo = *(const uint2*)(Mbw + u * 18 + qd * 4);
        uint2 hi = *(const uint2*)(Mbw + u * 18 + qd * 4 + 2);
        union { unsigned uu[4]; short8 s; } bm;
        bm.uu[0] = lo.x; bm.uu[1] = lo.y; bm.uu[2] = hi.x; bm.uu[3] = hi.y;
        Bm[ni] = bm.s;
    }
    // GEMM-Y
    f32x4 CY[2][2];
    #pragma unroll
    for (int mi = 0; mi < 2; ++mi)
        #pragma unroll
        for (int ni = 0; ni < 2; ++ni) {
            f32x4 z = {0.f, 0.f, 0.f, 0.f};
            CY[mi][ni] = __builtin_amdgcn_mfma_f32_16x16x32_bf16(Wf[mi], Bm[ni], z, 0, 0, 0);
        }
    // epilogue in place: res at xs[c=16mi+qd*4+r][w*25 + u] -> relu(Y*sc+bt+res)
    #pragma unroll
    for (int ni = 0; ni < 2; ++ni) {
        int u = 16 * ni + l16;
        if (u < V_) {
            #pragma unroll
            for (int mi = 0; mi < 2; ++mi) {
                #pragma unroll
                for (int r = 0; r < 4; ++r) {
                    float* rp = xs + (16 * mi + qd * 4 + r) * 132 + w * 25 + u;
                    float res = *rp;
                    float val = (CY[mi][ni][r] + cb4[mi][r] * Su[ni]) * sc4[mi][r]
                                + bt4[mi][r] + res;
                    *rp = val > 0.f ? val : 0.f;
                }
            }
        }
    }

    __syncthreads();

    // ---- coalesced nontemporal writeback (exact inverse of staging) ----
    float* og = out + ((size_t)(n * C_ + k * CG_) * T_ + tc * 4) * V_;
    #pragma unroll
    for (int ii = 0; ii < 4; ++ii) {
        int i = tid + ii * 256;
        if (i < 800) {
            int c = i / 25, col = i % 25;
            f32x4 f4 = *(const f32x4*)(xs + c * 132 + col * 4);
            __builtin_nontemporal_store(f4, (f32x4*)(og + (size_t)c * (T_ * V_) + col * 4));
        }
    }
}

extern "C" void kernel_launch(void* const* d_in, const int* in_sizes, int n_in,
                              void* d_out, int out_size, void* d_ws, size_t ws_size,
                              hipStream_t stream) {
    const float* x     = (const float*)d_in[0];
    const float* adjc  = (const float*)d_in[1];
    const float* edge  = (const float*)d_in[2];
    const float* hyper = (const float*)d_in[3];
    const float* alpha = (const float*)d_in[4];
    const float* tvw   = (const float*)d_in[5];
    const float* tvb   = (const float*)d_in[6];
    const float* t1w   = (const float*)d_in[7];
    const float* t1b   = (const float*)d_in[8];
    const float* t2w   = (const float*)d_in[9];
    const float* t2b   = (const float*)d_in[10];
    const float* cw    = (const float*)d_in[11];
    const float* cb    = (const float*)d_in[12];
    const float* gam   = (const float*)d_in[13];
    const float* bet   = (const float*)d_in[14];
    float* out = (float*)d_out;

    float* pooled = (float*)d_ws;                    // N*C*25 fp32
    float* adjR   = pooled + N_ * C_ * V_;           // N*K*32*32 fp32

    k_pool<<<dim3(N_ * 64 + 1), dim3(256), 0, stream>>>(
        x, hyper, pooled, out + (size_t)N_ * O_ * T_ * V_);
    k_graph<<<dim3(N_), dim3(256), 0, stream>>>(
        pooled, hyper, adjc, edge, alpha, tvw, tvb, t1w, t1b, t2w, t2b, adjR);
    k_main<<<dim3(N_ * K_ * 16), dim3(256), 0, stream>>>(
        x, hyper, adjR, cw, cb, gam, bet, out);
}

// Round 6
// 288.930 us; speedup vs baseline: 1.0314x; 1.0314x over previous
//
#include <hip/hip_runtime.h>
#include <hip/hip_bf16.h>

#define N_ 64
#define C_ 256
#define T_ 64
#define V_ 25
#define K_ 8
#define VN_ 5
#define VT_ 30
#define CG_ 32
#define H_ 8
#define O_ 256
#define OG_ 32
#define TOPK_ 9

typedef __attribute__((ext_vector_type(8))) short short8;
typedef __attribute__((ext_vector_type(4))) float f32x4;

__device__ __forceinline__ short bfbits(float f) {
    union { __hip_bfloat16 h; short s; } cv;
    cv.h = __float2bfloat16(f);
    return cv.s;
}
__device__ __forceinline__ short8 mk8(f32x4 a, f32x4 b) {
    short8 r;
    r[0] = bfbits(a[0]); r[1] = bfbits(a[1]); r[2] = bfbits(a[2]); r[3] = bfbits(a[3]);
    r[4] = bfbits(b[0]); r[5] = bfbits(b[1]); r[6] = bfbits(b[2]); r[7] = bfbits(b[3]);
    return r;
}
__device__ __forceinline__ short8 mk8f(const float* v) {
    short8 r;
    #pragma unroll
    for (int j = 0; j < 8; ++j) r[j] = bfbits(v[j]);
    return r;
}
__device__ __forceinline__ unsigned pkbf(float a, float b) {
    return (unsigned)(unsigned short)bfbits(a) | ((unsigned)(unsigned short)bfbits(b) << 16);
}

// ---------------- Kernel 1: coalesced T-mean pooling (+ output-tail copy) ----
__global__ __launch_bounds__(256) void k_pool(const float* __restrict__ x,
                                              const float* __restrict__ hyper,
                                              float* __restrict__ pooled,
                                              float* __restrict__ out_tail) {
    __shared__ float ls[6400];
    int b = blockIdx.x;
    int tid = threadIdx.x;
    if (b >= N_ * 64) {   // tail block: hyper passthrough (VN_*C_ = 1280)
        for (int i = tid; i < VN_ * C_; i += 256) out_tail[i] = hyper[i];
        return;
    }
    int n = b >> 6, c0 = (b & 63) * 4;
    const float4* xp = (const float4*)(x + (size_t)(n * C_ + c0) * (T_ * V_));
    for (int i = tid; i < 1600; i += 256) ((float4*)ls)[i] = xp[i];
    __syncthreads();
    if (tid < 100) {
        int c_l = tid / 25, v = tid % 25;
        const float* p = ls + c_l * 1600 + v;
        float s = 0.f;
        #pragma unroll
        for (int t = 0; t < T_; ++t) s += p[t * 25];
        pooled[(size_t)(n * C_ + c0 + c_l) * 25 + v] = s * (1.0f / T_);
    }
}

// ---------------- Kernel 2: graph construction -> adjR[n][k][u][v] (32x32) ---
__global__ __launch_bounds__(256) void k_graph(
    const float* __restrict__ pooled, const float* __restrict__ hyper,
    const float* __restrict__ adjc, const float* __restrict__ edge,
    const float* __restrict__ alpha,
    const float* __restrict__ to_v_w, const float* __restrict__ to_v_b,
    const float* __restrict__ to_w1_w, const float* __restrict__ to_w1_b,
    const float* __restrict__ to_w2_w, const float* __restrict__ to_w2_b,
    float* __restrict__ adjR) {
    __shared__ float smem[12000];
    float* vproj = smem;              // 1920: [k][v][h]
    float* w1s   = smem + 1920;       // 1920: [q][v], q=k*H+h
    float* pg    = smem + 3840;       // 7680: [c][v]  (phase A only)
    float* inc   = smem + 3840;       // 7200: [k][u][v] (phase B, aliases pg)
    float* wt    = smem + 11040;      // 240
    float* gv    = smem + 11280;      // 240
    float* rs    = smem + 11520;      // 240
    float* rsA   = smem + 11760;      // 240

    int n = blockIdx.x;
    int tid = threadIdx.x;
    for (int i = tid; i < C_ * V_; i += 256) {
        int c = i / V_, v = i % V_;
        pg[c * VT_ + v] = pooled[(size_t)n * C_ * V_ + i];
    }
    for (int i = tid; i < C_ * VN_; i += 256) {
        int c = i / VN_, j = i % VN_;
        pg[c * VT_ + V_ + j] = hyper[j * C_ + c];
    }
    __syncthreads();

    for (int i = tid; i < K_ * VT_ * H_; i += 256) {
        int k = i / (VT_ * H_);
        int r = i % (VT_ * H_);
        int v = r / H_, h = r % H_;
        const float* w = to_v_w + (k * H_ + h) * CG_;
        const float* pgk = pg + (k * CG_) * VT_ + v;
        float s = 0.f;
        #pragma unroll
        for (int c = 0; c < CG_; ++c) s += pgk[c * VT_] * w[c];
        vproj[(k * VT_ + v) * H_ + h] = s + to_v_b[k * H_ + h];
    }
    for (int i = tid; i < K_ * H_ * VT_; i += 256) {
        int k = i / (H_ * VT_);
        int r = i % (H_ * VT_);
        int h = r / VT_, v = r % VT_;
        const float* w = to_w1_w + (k * H_ + h) * CG_;
        const float* pgk = pg + (k * CG_) * VT_ + v;
        float s = 0.f;
        #pragma unroll
        for (int c = 0; c < CG_; ++c) s += pgk[c * VT_] * w[c];
        s += to_w1_b[k * H_ + h];
        w1s[(k * H_ + h) * VT_ + v] = (s > 0.f) ? s : 0.01f * s;  // leaky_relu
    }
    __syncthreads();   // pg dead after this barrier

    if (tid < K_ * VT_) {
        int k = tid / VT_;
        float s = to_w2_b[k];
        #pragma unroll
        for (int q = 0; q < K_ * H_; ++q)
            s += w1s[q * VT_ + (tid % VT_)] * to_w2_w[k * K_ * H_ + q];
        wt[tid] = tanhf(s);
        float sa = 0.f;
        const float* ea = edge + (size_t)tid * VT_;
        const float* aa = adjc + (size_t)tid * VT_;
        #pragma unroll
        for (int w2 = 0; w2 < VT_; ++w2) sa += fabsf(ea[w2] * aa[w2]);
        rsA[tid] = sa + 1e-8f;
    }
    if (tid < K_ * VT_) {
        int k = tid / VT_, u = tid % VT_;
        const float* vu = vproj + (k * VT_ + u) * H_;
        float nd[VT_];
        #pragma unroll
        for (int v = 0; v < VT_; ++v) {
            const float* vv = vproj + (k * VT_ + v) * H_;
            float d2 = 0.f;
            #pragma unroll
            for (int h = 0; h < H_; ++h) { float df = vu[h] - vv[h]; d2 += df * df; }
            nd[v] = (d2 > 0.f) ? -sqrtf(d2) : 0.0f;   // -dist
        }
        unsigned taken = 0;
        float vals[TOPK_]; int ids[TOPK_];
        for (int j = 0; j < TOPK_; ++j) {
            float best = -3.4e38f; int bi = 0;
            #pragma unroll
            for (int v = 0; v < VT_; ++v) {
                if (!((taken >> v) & 1u) && nd[v] > best) { best = nd[v]; bi = v; }
            }
            vals[j] = best; ids[j] = bi; taken |= (1u << bi);
        }
        float m = vals[0], se = 0.f, e[TOPK_];
        #pragma unroll
        for (int j = 0; j < TOPK_; ++j) { e[j] = expf(vals[j] - m); se += e[j]; }
        float invse = 1.f / se;
        float* row = inc + (size_t)tid * VT_;
        #pragma unroll
        for (int v = 0; v < VT_; ++v) row[v] = 0.f;
        for (int j = 0; j < TOPK_; ++j) row[ids[j]] = e[j] * invse;
    }
    __syncthreads();

    if (tid < K_ * VT_) {
        int k = tid / VT_, v = tid % VT_;
        float cs = 0.f;
        #pragma unroll
        for (int u = 0; u < VT_; ++u) cs += fabsf(inc[(k * VT_ + u) * VT_ + v]);
        float d = wt[tid] / (cs + 1e-8f);
        gv[tid] = wt[tid] * d;
        float s = 0.f;
        const float* row = inc + (size_t)tid * VT_;
        const float* w = wt + k * VT_;
        #pragma unroll
        for (int vv = 0; vv < VT_; ++vv) s += fabsf(row[vv] * w[vv]);
        rs[tid] = s + 1e-8f;
    }
    __syncthreads();

    // adjR[u][v] = adj_norm + relu(alpha)*hyper_adj, padded to 32x32 with zeros.
    float ar = alpha[0]; ar = ar > 0.f ? ar : 0.f;
    int kk = tid >> 5, uu = tid & 31;
    size_t obase = (size_t)n * K_ * 1024 + (size_t)kk * 1024 + (size_t)uu * 32;
    if (uu < VT_) {
        const float* ru = inc + (kk * VT_ + uu) * VT_;
        const float* g  = gv + kk * VT_;
        float tu[VT_];
        #pragma unroll
        for (int vv = 0; vv < VT_; ++vv) tu[vv] = ru[vv] * g[vv];
        float inv_rs = 1.0f / rs[kk * VT_ + uu];
        float inv_rsA = 1.0f / rsA[kk * VT_ + uu];
        for (int v = 0; v < 32; ++v) {
            float val = 0.f;
            if (v < VT_) {
                const float* rw = inc + (kk * VT_ + v) * VT_;
                float s = 0.f;
                #pragma unroll
                for (int vv = 0; vv < VT_; ++vv) s += tu[vv] * rw[vv];
                int ei = (kk * VT_ + uu) * VT_ + v;
                val = edge[ei] * adjc[ei] * inv_rsA + ar * (s * inv_rs);
            }
            adjR[obase + v] = val;
        }
    } else {
        #pragma unroll
        for (int v = 0; v < 32; ++v) adjR[obase + v] = 0.f;
    }
}

// ---------------- Kernel 3: row-contiguous LDS tile, b128 stage/writeback ----
// Round-5 structure (pure f32x4 staging, low VALU) at round-4 residency
// (4 blocks/CU): higher occupancy overflowed nt-store write-combining
// (WRITE_SIZE 109 -> 148 MB with identical store addresses).
// Block (n,k,tc): stage x[32c][4t*25v] -> xs[c][132] (100 used) as pure f32x4
// copies. Wave w owns t-window [w*25, w*25+25):
//   GEMM-M: M[c][u] = sum_v xv[c][v]*adjR[u][v]
//   M -> per-wave LDS Mb packed bf16 (row u: 18 dwords)
//   GEMM-Y: Y[o][u] = sum_c W[o][c]*M[c][u] (+ cb[o]*S[u])
//   Epilogue in place at xs[c][w*25+u] (disjoint per-wave windows).
// Barrier + f32x4 nontemporal writeback (exact inverse of staging).
__global__ __launch_bounds__(256, 4) void k_main(
    const float* __restrict__ x, const float* __restrict__ hyper,
    const float* __restrict__ adjR,
    const float* __restrict__ conv_w, const float* __restrict__ conv_b,
    const float* __restrict__ gamma, const float* __restrict__ beta,
    float* __restrict__ out) {
    __shared__ __align__(16) float xs[32 * 132];        // [c][132], 100 used
    __shared__ __align__(16) unsigned Mb[4 * 32 * 18];  // per-wave [u][18]

    int b = blockIdx.x;
    int tc = b & 15, k = (b >> 4) & 7, n = b >> 7;
    int tid = threadIdx.x;
    int w = tid >> 6;
    int lane = tid & 63;
    int qd = lane >> 4;        // quad 0..3
    int l16 = lane & 15;

    // ---- stage x slice (32c x 100 floats) coalesced: 800 f32x4 copies ----
    const float* xg = x + ((size_t)(n * C_ + k * CG_) * T_ + tc * 4) * V_;
    #pragma unroll
    for (int ii = 0; ii < 4; ++ii) {
        int i = tid + ii * 256;
        if (i < 800) {
            int c = i / 25, col = i % 25;
            f32x4 f4 = *(const f32x4*)(xg + (size_t)c * (T_ * V_) + col * 4);
            *(f32x4*)(xs + c * 132 + col * 4) = f4;
        }
    }

    // ---- block-constant register fragments (issued while staging in flight) --
    short8 Wf[2];   // W[o=16mi+l16][c=qd*8+j]
    #pragma unroll
    for (int mi = 0; mi < 2; ++mi) {
        const float* wp = conv_w + (size_t)(k * OG_ + 16 * mi + l16) * CG_ + qd * 8;
        Wf[mi] = mk8(*(const f32x4*)wp, *(const f32x4*)(wp + 4));
    }
    short8 Bf[2]; float Su[2];   // adjR[u=16ni+l16][v=qd*8+j]; f32 row sums S[u]
    #pragma unroll
    for (int ni = 0; ni < 2; ++ni) {
        const float* ap = adjR + (((size_t)(n * K_ + k)) * 32 + 16 * ni + l16) * 32 + qd * 8;
        f32x4 a0 = *(const f32x4*)ap, a1 = *(const f32x4*)(ap + 4);
        Bf[ni] = mk8(a0, a1);
        float s = a0[0] + a0[1] + a0[2] + a0[3] + a1[0] + a1[1] + a1[2] + a1[3];
        s += __shfl_xor(s, 16);
        s += __shfl_xor(s, 32);
        Su[ni] = s;
    }
    f32x4 cb4[2], sc4[2], bt4[2];   // per o-quad: o = 16mi + qd*4 + r
    #pragma unroll
    for (int mi = 0; mi < 2; ++mi) {
        int o0 = k * OG_ + 16 * mi + qd * 4;
        cb4[mi] = *(const f32x4*)(conv_b + o0);
        f32x4 g = *(const f32x4*)(gamma + o0);
        #pragma unroll
        for (int r = 0; r < 4; ++r) g[r] *= 0.999995000037f;  // 1/sqrt(1+1e-5)
        sc4[mi] = g;
        bt4[mi] = *(const f32x4*)(beta + o0);
    }
    short8 Ht[2];   // qd==3 A-template: slot0=x[..][24] (per t), 1..5=hyper, 6,7=0
    #pragma unroll
    for (int mi = 0; mi < 2; ++mi) {
        int c = k * CG_ + 16 * mi + l16;
        short8 h;
        h[0] = 0; h[6] = 0; h[7] = 0;
        #pragma unroll
        for (int j = 0; j < 5; ++j) h[1 + j] = bfbits(hyper[j * C_ + c]);
        Ht[mi] = h;
    }

    __syncthreads();

    unsigned* Mbw = Mb + w * (32 * 18);

    // A-frags: xv[c=16mi+l16][v=qd*8+j] at xs[c*132 + w*25 + v]
    short8 Ax[2];
    #pragma unroll
    for (int mi = 0; mi < 2; ++mi) {
        const float* xp = xs + (16 * mi + l16) * 132 + w * 25;
        if (qd < 3) {
            float va[8];
            #pragma unroll
            for (int j = 0; j < 8; ++j) va[j] = xp[qd * 8 + j];
            Ax[mi] = mk8f(va);
        } else {
            short8 h = Ht[mi];
            h[0] = bfbits(xp[24]);
            Ax[mi] = h;
        }
    }
    // GEMM-M: lane(qd,l16) gets M[c=16mi+qd*4+r][u=16ni+l16]
    f32x4 CM[2][2];
    #pragma unroll
    for (int mi = 0; mi < 2; ++mi)
        #pragma unroll
        for (int ni = 0; ni < 2; ++ni) {
            f32x4 z = {0.f, 0.f, 0.f, 0.f};
            CM[mi][ni] = __builtin_amdgcn_mfma_f32_16x16x32_bf16(Ax[mi], Bf[ni], z, 0, 0, 0);
        }
    // M -> Mb packed bf16: row u, dword d = 8mi + 2qd + {0,1} holds c {2d,2d+1}
    #pragma unroll
    for (int mi = 0; mi < 2; ++mi)
        #pragma unroll
        for (int ni = 0; ni < 2; ++ni) {
            int u = 16 * ni + l16;
            uint2 pr;
            pr.x = pkbf(CM[mi][ni][0], CM[mi][ni][1]);
            pr.y = pkbf(CM[mi][ni][2], CM[mi][ni][3]);
            *(uint2*)(Mbw + u * 18 + 8 * mi + 2 * qd) = pr;
        }
    // B-frags of GEMM-Y: M[u=16ni+l16][c=qd*8+j] -> dwords qd*4..qd*4+3
    short8 Bm[2];
    #pragma unroll
    for (int ni = 0; ni < 2; ++ni) {
        int u = 16 * ni + l16;
        uint2 lo = *(const uint2*)(Mbw + u * 18 + qd * 4);
        uint2 hi = *(const uint2*)(Mbw + u * 18 + qd * 4 + 2);
        union { unsigned uu[4]; short8 s; } bm;
        bm.uu[0] = lo.x; bm.uu[1] = lo.y; bm.uu[2] = hi.x; bm.uu[3] = hi.y;
        Bm[ni] = bm.s;
    }
    // GEMM-Y
    f32x4 CY[2][2];
    #pragma unroll
    for (int mi = 0; mi < 2; ++mi)
        #pragma unroll
        for (int ni = 0; ni < 2; ++ni) {
            f32x4 z = {0.f, 0.f, 0.f, 0.f};
            CY[mi][ni] = __builtin_amdgcn_mfma_f32_16x16x32_bf16(Wf[mi], Bm[ni], z, 0, 0, 0);
        }
    // epilogue in place: res at xs[c=16mi+qd*4+r][w*25 + u] -> relu(Y*sc+bt+res)
    #pragma unroll
    for (int ni = 0; ni < 2; ++ni) {
        int u = 16 * ni + l16;
        if (u < V_) {
            #pragma unroll
            for (int mi = 0; mi < 2; ++mi) {
                #pragma unroll
                for (int r = 0; r < 4; ++r) {
                    float* rp = xs + (16 * mi + qd * 4 + r) * 132 + w * 25 + u;
                    float res = *rp;
                    float val = (CY[mi][ni][r] + cb4[mi][r] * Su[ni]) * sc4[mi][r]
                                + bt4[mi][r] + res;
                    *rp = val > 0.f ? val : 0.f;
                }
            }
        }
    }

    __syncthreads();

    // ---- coalesced nontemporal writeback (exact inverse of staging) ----
    float* og = out + ((size_t)(n * C_ + k * CG_) * T_ + tc * 4) * V_;
    #pragma unroll
    for (int ii = 0; ii < 4; ++ii) {
        int i = tid + ii * 256;
        if (i < 800) {
            int c = i / 25, col = i % 25;
            f32x4 f4 = *(const f32x4*)(xs + c * 132 + col * 4);
            __builtin_nontemporal_store(f4, (f32x4*)(og + (size_t)c * (T_ * V_) + col * 4));
        }
    }
}

extern "C" void kernel_launch(void* const* d_in, const int* in_sizes, int n_in,
                              void* d_out, int out_size, void* d_ws, size_t ws_size,
                              hipStream_t stream) {
    const float* x     = (const float*)d_in[0];
    const float* adjc  = (const float*)d_in[1];
    const float* edge  = (const float*)d_in[2];
    const float* hyper = (const float*)d_in[3];
    const float* alpha = (const float*)d_in[4];
    const float* tvw   = (const float*)d_in[5];
    const float* tvb   = (const float*)d_in[6];
    const float* t1w   = (const float*)d_in[7];
    const float* t1b   = (const float*)d_in[8];
    const float* t2w   = (const float*)d_in[9];
    const float* t2b   = (const float*)d_in[10];
    const float* cw    = (const float*)d_in[11];
    const float* cb    = (const float*)d_in[12];
    const float* gam   = (const float*)d_in[13];
    const float* bet   = (const float*)d_in[14];
    float* out = (float*)d_out;

    float* pooled = (float*)d_ws;                    // N*C*25 fp32
    float* adjR   = pooled + N_ * C_ * V_;           // N*K*32*32 fp32

    k_pool<<<dim3(N_ * 64 + 1), dim3(256), 0, stream>>>(
        x, hyper, pooled, out + (size_t)N_ * O_ * T_ * V_);
    k_graph<<<dim3(N_), dim3(256), 0, stream>>>(
        pooled, hyper, adjc, edge, alpha, tvw, tvb, t1w, t1b, t2w, t2b, adjR);
    k_main<<<dim3(N_ * K_ * 16), dim3(256), 0, stream>>>(
        x, hyper, adjR, cw, cb, gam, bet, out);
}

// Round 7
// 268.965 us; speedup vs baseline: 1.1080x; 1.0742x over previous
//
#include <hip/hip_runtime.h>
#include <hip/hip_bf16.h>

#define N_ 64
#define C_ 256
#define T_ 64
#define V_ 25
#define K_ 8
#define VN_ 5
#define VT_ 30
#define CG_ 32
#define H_ 8
#define O_ 256
#define OG_ 32
#define TOPK_ 9

typedef __attribute__((ext_vector_type(8))) short short8;
typedef __attribute__((ext_vector_type(4))) float f32x4;

__device__ __forceinline__ short bfbits(float f) {
    union { __hip_bfloat16 h; short s; } cv;
    cv.h = __float2bfloat16(f);
    return cv.s;
}
__device__ __forceinline__ short8 mk8(f32x4 a, f32x4 b) {
    short8 r;
    r[0] = bfbits(a[0]); r[1] = bfbits(a[1]); r[2] = bfbits(a[2]); r[3] = bfbits(a[3]);
    r[4] = bfbits(b[0]); r[5] = bfbits(b[1]); r[6] = bfbits(b[2]); r[7] = bfbits(b[3]);
    return r;
}
__device__ __forceinline__ short8 mk8f(const float* v) {
    short8 r;
    #pragma unroll
    for (int j = 0; j < 8; ++j) r[j] = bfbits(v[j]);
    return r;
}
__device__ __forceinline__ unsigned pkbf(float a, float b) {
    return (unsigned)(unsigned short)bfbits(a) | ((unsigned)(unsigned short)bfbits(b) << 16);
}

// ---------------- Kernel 1: coalesced T-mean pooling (+ output-tail copy) ----
__global__ __launch_bounds__(256) void k_pool(const float* __restrict__ x,
                                              const float* __restrict__ hyper,
                                              float* __restrict__ pooled,
                                              float* __restrict__ out_tail) {
    __shared__ float ls[6400];
    int b = blockIdx.x;
    int tid = threadIdx.x;
    if (b >= N_ * 64) {   // tail block: hyper passthrough (VN_*C_ = 1280)
        for (int i = tid; i < VN_ * C_; i += 256) out_tail[i] = hyper[i];
        return;
    }
    int n = b >> 6, c0 = (b & 63) * 4;
    const float4* xp = (const float4*)(x + (size_t)(n * C_ + c0) * (T_ * V_));
    for (int i = tid; i < 1600; i += 256) ((float4*)ls)[i] = xp[i];
    __syncthreads();
    if (tid < 100) {
        int c_l = tid / 25, v = tid % 25;
        const float* p = ls + c_l * 1600 + v;
        float s = 0.f;
        #pragma unroll
        for (int t = 0; t < T_; ++t) s += p[t * 25];
        pooled[(size_t)(n * C_ + c0 + c_l) * 25 + v] = s * (1.0f / T_);
    }
}

// ---------------- Kernel 2: graph construction, one block per (n,k) ---------
// 8x more blocks than before (512 vs 64; was 0.6% HBM / 2.9% VALU / 2.7% occ
// latency-bound). Cross-k dependency (to_w2 einsum over q=K*H) handled by
// redundantly computing w1s for all q in every block (61k FMA - trivial).
// All inner loops verbatim from the verified one-block-per-n version.
__global__ __launch_bounds__(256) void k_graph(
    const float* __restrict__ pooled, const float* __restrict__ hyper,
    const float* __restrict__ adjc, const float* __restrict__ edge,
    const float* __restrict__ alpha,
    const float* __restrict__ to_v_w, const float* __restrict__ to_v_b,
    const float* __restrict__ to_w1_w, const float* __restrict__ to_w1_b,
    const float* __restrict__ to_w2_w, const float* __restrict__ to_w2_b,
    float* __restrict__ adjR) {
    __shared__ float pg[C_ * VT_];      // 7680: [c][v] full pooled slice
    __shared__ float w1s[K_ * H_ * VT_];// 1920: [q][v] (all q - redundant)
    __shared__ float vproj[VT_ * H_];   // 240:  [v][h] own k
    __shared__ float inc[VT_ * VT_];    // 900:  [u][v] own k
    __shared__ float wt30[VT_], gv30[VT_], rs30[VT_], rsA30[VT_];

    int b = blockIdx.x;
    int n = b >> 3, k = b & 7;
    int tid = threadIdx.x;

    // ---- stage pooled[n] + hyper -> pg[c][30] ----
    for (int i = tid; i < C_ * V_; i += 256) {
        int c = i / V_, v = i % V_;
        pg[c * VT_ + v] = pooled[(size_t)n * C_ * V_ + i];
    }
    for (int i = tid; i < C_ * VN_; i += 256) {
        int c = i / VN_, j = i % VN_;
        pg[c * VT_ + V_ + j] = hyper[j * C_ + c];
    }
    __syncthreads();

    // ---- vproj for own k (240 outputs) ----
    if (tid < VT_ * H_) {
        int v = tid / H_, h = tid % H_;
        const float* w = to_v_w + (k * H_ + h) * CG_;
        const float* pgk = pg + (k * CG_) * VT_ + v;
        float s = 0.f;
        #pragma unroll
        for (int c = 0; c < CG_; ++c) s += pgk[c * VT_] * w[c];
        vproj[v * H_ + h] = s + to_v_b[k * H_ + h];
    }
    // ---- w1s for ALL q (1920 outputs, 8x redundant across k-blocks) ----
    for (int i = tid; i < K_ * H_ * VT_; i += 256) {
        int q = i / VT_, v = i % VT_;
        int k2 = q / H_;
        const float* w = to_w1_w + q * CG_;
        const float* pgk = pg + (k2 * CG_) * VT_ + v;
        float s = 0.f;
        #pragma unroll
        for (int c = 0; c < CG_; ++c) s += pgk[c * VT_] * w[c];
        s += to_w1_b[q];
        w1s[q * VT_ + v] = (s > 0.f) ? s : 0.01f * s;  // leaky_relu
    }
    __syncthreads();

    // ---- phase split across waves: topk (w0), wt (w1), rsA (w2) ----
    if (tid < VT_) {
        int u = tid;
        const float* vu = vproj + u * H_;
        float nd[VT_];
        #pragma unroll
        for (int v = 0; v < VT_; ++v) {
            const float* vv = vproj + v * H_;
            float d2 = 0.f;
            #pragma unroll
            for (int h = 0; h < H_; ++h) { float df = vu[h] - vv[h]; d2 += df * df; }
            nd[v] = (d2 > 0.f) ? -sqrtf(d2) : 0.0f;   // -dist
        }
        unsigned taken = 0;
        float vals[TOPK_]; int ids[TOPK_];
        for (int j = 0; j < TOPK_; ++j) {
            float best = -3.4e38f; int bi = 0;
            #pragma unroll
            for (int v = 0; v < VT_; ++v) {
                if (!((taken >> v) & 1u) && nd[v] > best) { best = nd[v]; bi = v; }
            }
            vals[j] = best; ids[j] = bi; taken |= (1u << bi);
        }
        float m = vals[0], se = 0.f, e[TOPK_];
        #pragma unroll
        for (int j = 0; j < TOPK_; ++j) { e[j] = expf(vals[j] - m); se += e[j]; }
        float invse = 1.f / se;
        float* row = inc + u * VT_;
        #pragma unroll
        for (int v = 0; v < VT_; ++v) row[v] = 0.f;
        for (int j = 0; j < TOPK_; ++j) row[ids[j]] = e[j] * invse;
    } else if (tid >= 64 && tid < 64 + VT_) {
        int v = tid - 64;
        float s = to_w2_b[k];
        #pragma unroll
        for (int q = 0; q < K_ * H_; ++q)
            s += w1s[q * VT_ + v] * to_w2_w[k * K_ * H_ + q];
        wt30[v] = tanhf(s);
    } else if (tid >= 128 && tid < 128 + VT_) {
        int u = tid - 128;
        float sa = 0.f;
        const float* ea = edge + (size_t)(k * VT_ + u) * VT_;
        const float* aa = adjc + (size_t)(k * VT_ + u) * VT_;
        #pragma unroll
        for (int w2 = 0; w2 < VT_; ++w2) sa += fabsf(ea[w2] * aa[w2]);
        rsA30[u] = sa + 1e-8f;
    }
    __syncthreads();

    // ---- gv (w0) and rs (w1) ----
    if (tid < VT_) {
        int v = tid;
        float cs = 0.f;
        #pragma unroll
        for (int u = 0; u < VT_; ++u) cs += fabsf(inc[u * VT_ + v]);
        float d = wt30[v] / (cs + 1e-8f);
        gv30[v] = wt30[v] * d;
    } else if (tid >= 64 && tid < 64 + VT_) {
        int u = tid - 64;
        float s = 0.f;
        const float* row = inc + u * VT_;
        #pragma unroll
        for (int vv = 0; vv < VT_; ++vv) s += fabsf(row[vv] * wt30[vv]);
        rs30[u] = s + 1e-8f;
    }
    __syncthreads();

    // ---- adjR[u][v] for own k: 1024 outputs, 4 per thread ----
    float ar = alpha[0]; ar = ar > 0.f ? ar : 0.f;
    size_t obase = (size_t)b * 1024;
    #pragma unroll
    for (int ii = 0; ii < 4; ++ii) {
        int i = tid + ii * 256;
        int u = i >> 5, v = i & 31;
        float val = 0.f;
        if (u < VT_ && v < VT_) {
            const float* ru = inc + u * VT_;
            const float* rw = inc + v * VT_;
            float s = 0.f;
            #pragma unroll
            for (int vv = 0; vv < VT_; ++vv) s += ru[vv] * gv30[vv] * rw[vv];
            float inv_rs = 1.0f / rs30[u];
            float inv_rsA = 1.0f / rsA30[u];
            int ei = (k * VT_ + u) * VT_ + v;
            val = edge[ei] * adjc[ei] * inv_rsA + ar * (s * inv_rs);
        }
        adjR[obase + i] = val;
    }
}

// ---------------- Kernel 3: row-contiguous LDS tile, b128 stage/writeback ----
// (unchanged from round 6: pure f32x4 staging at 4 blocks/CU)
__global__ __launch_bounds__(256, 4) void k_main(
    const float* __restrict__ x, const float* __restrict__ hyper,
    const float* __restrict__ adjR,
    const float* __restrict__ conv_w, const float* __restrict__ conv_b,
    const float* __restrict__ gamma, const float* __restrict__ beta,
    float* __restrict__ out) {
    __shared__ __align__(16) float xs[32 * 132];        // [c][132], 100 used
    __shared__ __align__(16) unsigned Mb[4 * 32 * 18];  // per-wave [u][18]

    int b = blockIdx.x;
    int tc = b & 15, k = (b >> 4) & 7, n = b >> 7;
    int tid = threadIdx.x;
    int w = tid >> 6;
    int lane = tid & 63;
    int qd = lane >> 4;        // quad 0..3
    int l16 = lane & 15;

    // ---- stage x slice (32c x 100 floats) coalesced: 800 f32x4 copies ----
    const float* xg = x + ((size_t)(n * C_ + k * CG_) * T_ + tc * 4) * V_;
    #pragma unroll
    for (int ii = 0; ii < 4; ++ii) {
        int i = tid + ii * 256;
        if (i < 800) {
            int c = i / 25, col = i % 25;
            f32x4 f4 = *(const f32x4*)(xg + (size_t)c * (T_ * V_) + col * 4);
            *(f32x4*)(xs + c * 132 + col * 4) = f4;
        }
    }

    // ---- block-constant register fragments (issued while staging in flight) --
    short8 Wf[2];   // W[o=16mi+l16][c=qd*8+j]
    #pragma unroll
    for (int mi = 0; mi < 2; ++mi) {
        const float* wp = conv_w + (size_t)(k * OG_ + 16 * mi + l16) * CG_ + qd * 8;
        Wf[mi] = mk8(*(const f32x4*)wp, *(const f32x4*)(wp + 4));
    }
    short8 Bf[2]; float Su[2];   // adjR[u=16ni+l16][v=qd*8+j]; f32 row sums S[u]
    #pragma unroll
    for (int ni = 0; ni < 2; ++ni) {
        const float* ap = adjR + (((size_t)(n * K_ + k)) * 32 + 16 * ni + l16) * 32 + qd * 8;
        f32x4 a0 = *(const f32x4*)ap, a1 = *(const f32x4*)(ap + 4);
        Bf[ni] = mk8(a0, a1);
        float s = a0[0] + a0[1] + a0[2] + a0[3] + a1[0] + a1[1] + a1[2] + a1[3];
        s += __shfl_xor(s, 16);
        s += __shfl_xor(s, 32);
        Su[ni] = s;
    }
    f32x4 cb4[2], sc4[2], bt4[2];   // per o-quad: o = 16mi + qd*4 + r
    #pragma unroll
    for (int mi = 0; mi < 2; ++mi) {
        int o0 = k * OG_ + 16 * mi + qd * 4;
        cb4[mi] = *(const f32x4*)(conv_b + o0);
        f32x4 g = *(const f32x4*)(gamma + o0);
        #pragma unroll
        for (int r = 0; r < 4; ++r) g[r] *= 0.999995000037f;  // 1/sqrt(1+1e-5)
        sc4[mi] = g;
        bt4[mi] = *(const f32x4*)(beta + o0);
    }
    short8 Ht[2];   // qd==3 A-template: slot0=x[..][24] (per t), 1..5=hyper, 6,7=0
    #pragma unroll
    for (int mi = 0; mi < 2; ++mi) {
        int c = k * CG_ + 16 * mi + l16;
        short8 h;
        h[0] = 0; h[6] = 0; h[7] = 0;
        #pragma unroll
        for (int j = 0; j < 5; ++j) h[1 + j] = bfbits(hyper[j * C_ + c]);
        Ht[mi] = h;
    }

    __syncthreads();

    unsigned* Mbw = Mb + w * (32 * 18);

    // A-frags: xv[c=16mi+l16][v=qd*8+j] at xs[c*132 + w*25 + v]
    short8 Ax[2];
    #pragma unroll
    for (int mi = 0; mi < 2; ++mi) {
        const float* xp = xs + (16 * mi + l16) * 132 + w * 25;
        if (qd < 3) {
            float va[8];
            #pragma unroll
            for (int j = 0; j < 8; ++j) va[j] = xp[qd * 8 + j];
            Ax[mi] = mk8f(va);
        } else {
            short8 h = Ht[mi];
            h[0] = bfbits(xp[24]);
            Ax[mi] = h;
        }
    }
    // GEMM-M: lane(qd,l16) gets M[c=16mi+qd*4+r][u=16ni+l16]
    f32x4 CM[2][2];
    #pragma unroll
    for (int mi = 0; mi < 2; ++mi)
        #pragma unroll
        for (int ni = 0; ni < 2; ++ni) {
            f32x4 z = {0.f, 0.f, 0.f, 0.f};
            CM[mi][ni] = __builtin_amdgcn_mfma_f32_16x16x32_bf16(Ax[mi], Bf[ni], z, 0, 0, 0);
        }
    // M -> Mb packed bf16: row u, dword d = 8mi + 2qd + {0,1} holds c {2d,2d+1}
    #pragma unroll
    for (int mi = 0; mi < 2; ++mi)
        #pragma unroll
        for (int ni = 0; ni < 2; ++ni) {
            int u = 16 * ni + l16;
            uint2 pr;
            pr.x = pkbf(CM[mi][ni][0], CM[mi][ni][1]);
            pr.y = pkbf(CM[mi][ni][2], CM[mi][ni][3]);
            *(uint2*)(Mbw + u * 18 + 8 * mi + 2 * qd) = pr;
        }
    // B-frags of GEMM-Y: M[u=16ni+l16][c=qd*8+j] -> dwords qd*4..qd*4+3
    short8 Bm[2];
    #pragma unroll
    for (int ni = 0; ni < 2; ++ni) {
        int u = 16 * ni + l16;
        uint2 lo = *(const uint2*)(Mbw + u * 18 + qd * 4);
        uint2 hi = *(const uint2*)(Mbw + u * 18 + qd * 4 + 2);
        union { unsigned uu[4]; short8 s; } bm;
        bm.uu[0] = lo.x; bm.uu[1] = lo.y; bm.uu[2] = hi.x; bm.uu[3] = hi.y;
        Bm[ni] = bm.s;
    }
    // GEMM-Y
    f32x4 CY[2][2];
    #pragma unroll
    for (int mi = 0; mi < 2; ++mi)
        #pragma unroll
        for (int ni = 0; ni < 2; ++ni) {
            f32x4 z = {0.f, 0.f, 0.f, 0.f};
            CY[mi][ni] = __builtin_amdgcn_mfma_f32_16x16x32_bf16(Wf[mi], Bm[ni], z, 0, 0, 0);
        }
    // epilogue in place: res at xs[c=16mi+qd*4+r][w*25 + u] -> relu(Y*sc+bt+res)
    #pragma unroll
    for (int ni = 0; ni < 2; ++ni) {
        int u = 16 * ni + l16;
        if (u < V_) {
            #pragma unroll
            for (int mi = 0; mi < 2; ++mi) {
                #pragma unroll
                for (int r = 0; r < 4; ++r) {
                    float* rp = xs + (16 * mi + qd * 4 + r) * 132 + w * 25 + u;
                    float res = *rp;
                    float val = (CY[mi][ni][r] + cb4[mi][r] * Su[ni]) * sc4[mi][r]
                                + bt4[mi][r] + res;
                    *rp = val > 0.f ? val : 0.f;
                }
            }
        }
    }

    __syncthreads();

    // ---- coalesced nontemporal writeback (exact inverse of staging) ----
    float* og = out + ((size_t)(n * C_ + k * CG_) * T_ + tc * 4) * V_;
    #pragma unroll
    for (int ii = 0; ii < 4; ++ii) {
        int i = tid + ii * 256;
        if (i < 800) {
            int c = i / 25, col = i % 25;
            f32x4 f4 = *(const f32x4*)(xs + c * 132 + col * 4);
            __builtin_nontemporal_store(f4, (f32x4*)(og + (size_t)c * (T_ * V_) + col * 4));
        }
    }
}

extern "C" void kernel_launch(void* const* d_in, const int* in_sizes, int n_in,
                              void* d_out, int out_size, void* d_ws, size_t ws_size,
                              hipStream_t stream) {
    const float* x     = (const float*)d_in[0];
    const float* adjc  = (const float*)d_in[1];
    const float* edge  = (const float*)d_in[2];
    const float* hyper = (const float*)d_in[3];
    const float* alpha = (const float*)d_in[4];
    const float* tvw   = (const float*)d_in[5];
    const float* tvb   = (const float*)d_in[6];
    const float* t1w   = (const float*)d_in[7];
    const float* t1b   = (const float*)d_in[8];
    const float* t2w   = (const float*)d_in[9];
    const float* t2b   = (const float*)d_in[10];
    const float* cw    = (const float*)d_in[11];
    const float* cb    = (const float*)d_in[12];
    const float* gam   = (const float*)d_in[13];
    const float* bet   = (const float*)d_in[14];
    float* out = (float*)d_out;

    float* pooled = (float*)d_ws;                    // N*C*25 fp32
    float* adjR   = pooled + N_ * C_ * V_;           // N*K*32*32 fp32

    k_pool<<<dim3(N_ * 64 + 1), dim3(256), 0, stream>>>(
        x, hyper, pooled, out + (size_t)N_ * O_ * T_ * V_);
    k_graph<<<dim3(N_ * K_), dim3(256), 0, stream>>>(
        pooled, hyper, adjc, edge, alpha, tvw, tvb, t1w, t1b, t2w, t2b, adjR);
    k_main<<<dim3(N_ * K_ * 16), dim3(256), 0, stream>>>(
        x, hyper, adjR, cw, cb, gam, bet, out);
}

// Round 8
// 260.473 us; speedup vs baseline: 1.1441x; 1.0326x over previous
//
#include <hip/hip_runtime.h>
#include <hip/hip_bf16.h>

#define N_ 64
#define C_ 256
#define T_ 64
#define V_ 25
#define K_ 8
#define VN_ 5
#define VT_ 30
#define CG_ 32
#define H_ 8
#define O_ 256
#define OG_ 32
#define TOPK_ 9

typedef __attribute__((ext_vector_type(8))) short short8;
typedef __attribute__((ext_vector_type(4))) float f32x4;

__device__ __forceinline__ short bfbits(float f) {
    union { __hip_bfloat16 h; short s; } cv;
    cv.h = __float2bfloat16(f);
    return cv.s;
}
__device__ __forceinline__ short8 mk8(f32x4 a, f32x4 b) {
    short8 r;
    r[0] = bfbits(a[0]); r[1] = bfbits(a[1]); r[2] = bfbits(a[2]); r[3] = bfbits(a[3]);
    r[4] = bfbits(b[0]); r[5] = bfbits(b[1]); r[6] = bfbits(b[2]); r[7] = bfbits(b[3]);
    return r;
}
__device__ __forceinline__ short8 mk8f(const float* v) {
    short8 r;
    #pragma unroll
    for (int j = 0; j < 8; ++j) r[j] = bfbits(v[j]);
    return r;
}
__device__ __forceinline__ unsigned pkbf(float a, float b) {
    return (unsigned)(unsigned short)bfbits(a) | ((unsigned)(unsigned short)bfbits(b) << 16);
}

// ---------------- Kernel 1: coalesced T-mean pooling (+ output-tail copy) ----
__global__ __launch_bounds__(256) void k_pool(const float* __restrict__ x,
                                              const float* __restrict__ hyper,
                                              float* __restrict__ pooled,
                                              float* __restrict__ out_tail) {
    __shared__ float ls[6400];
    int b = blockIdx.x;
    int tid = threadIdx.x;
    if (b >= N_ * 64) {   // tail block: hyper passthrough (VN_*C_ = 1280)
        for (int i = tid; i < VN_ * C_; i += 256) out_tail[i] = hyper[i];
        return;
    }
    int n = b >> 6, c0 = (b & 63) * 4;
    const float4* xp = (const float4*)(x + (size_t)(n * C_ + c0) * (T_ * V_));
    for (int i = tid; i < 1600; i += 256) ((float4*)ls)[i] = xp[i];
    __syncthreads();
    if (tid < 100) {
        int c_l = tid / 25, v = tid % 25;
        const float* p = ls + c_l * 1600 + v;
        float s = 0.f;
        #pragma unroll
        for (int t = 0; t < T_; ++t) s += p[t * 25];
        pooled[(size_t)(n * C_ + c0 + c_l) * 25 + v] = s * (1.0f / T_);
    }
}

// ---------------- Kernel 2: graph construction, one block per (n,k) ---------
__global__ __launch_bounds__(256) void k_graph(
    const float* __restrict__ pooled, const float* __restrict__ hyper,
    const float* __restrict__ adjc, const float* __restrict__ edge,
    const float* __restrict__ alpha,
    const float* __restrict__ to_v_w, const float* __restrict__ to_v_b,
    const float* __restrict__ to_w1_w, const float* __restrict__ to_w1_b,
    const float* __restrict__ to_w2_w, const float* __restrict__ to_w2_b,
    float* __restrict__ adjR) {
    __shared__ float pg[C_ * VT_];      // 7680: [c][v] full pooled slice
    __shared__ float w1s[K_ * H_ * VT_];// 1920: [q][v] (all q - redundant)
    __shared__ float vproj[VT_ * H_];   // 240:  [v][h] own k
    __shared__ float inc[VT_ * VT_];    // 900:  [u][v] own k
    __shared__ float wt30[VT_], gv30[VT_], rs30[VT_], rsA30[VT_];

    int b = blockIdx.x;
    int n = b >> 3, k = b & 7;
    int tid = threadIdx.x;

    // ---- stage pooled[n] + hyper -> pg[c][30] ----
    for (int i = tid; i < C_ * V_; i += 256) {
        int c = i / V_, v = i % V_;
        pg[c * VT_ + v] = pooled[(size_t)n * C_ * V_ + i];
    }
    for (int i = tid; i < C_ * VN_; i += 256) {
        int c = i / VN_, j = i % VN_;
        pg[c * VT_ + V_ + j] = hyper[j * C_ + c];
    }
    __syncthreads();

    // ---- vproj for own k (240 outputs) ----
    if (tid < VT_ * H_) {
        int v = tid / H_, h = tid % H_;
        const float* w = to_v_w + (k * H_ + h) * CG_;
        const float* pgk = pg + (k * CG_) * VT_ + v;
        float s = 0.f;
        #pragma unroll
        for (int c = 0; c < CG_; ++c) s += pgk[c * VT_] * w[c];
        vproj[v * H_ + h] = s + to_v_b[k * H_ + h];
    }
    // ---- w1s for ALL q (1920 outputs, 8x redundant across k-blocks) ----
    for (int i = tid; i < K_ * H_ * VT_; i += 256) {
        int q = i / VT_, v = i % VT_;
        int k2 = q / H_;
        const float* w = to_w1_w + q * CG_;
        const float* pgk = pg + (k2 * CG_) * VT_ + v;
        float s = 0.f;
        #pragma unroll
        for (int c = 0; c < CG_; ++c) s += pgk[c * VT_] * w[c];
        s += to_w1_b[q];
        w1s[q * VT_ + v] = (s > 0.f) ? s : 0.01f * s;  // leaky_relu
    }
    __syncthreads();

    // ---- phase split across waves: topk (w0), wt (w1), rsA (w2) ----
    if (tid < VT_) {
        int u = tid;
        const float* vu = vproj + u * H_;
        float nd[VT_];
        #pragma unroll
        for (int v = 0; v < VT_; ++v) {
            const float* vv = vproj + v * H_;
            float d2 = 0.f;
            #pragma unroll
            for (int h = 0; h < H_; ++h) { float df = vu[h] - vv[h]; d2 += df * df; }
            nd[v] = (d2 > 0.f) ? -sqrtf(d2) : 0.0f;   // -dist
        }
        unsigned taken = 0;
        float vals[TOPK_]; int ids[TOPK_];
        for (int j = 0; j < TOPK_; ++j) {
            float best = -3.4e38f; int bi = 0;
            #pragma unroll
            for (int v = 0; v < VT_; ++v) {
                if (!((taken >> v) & 1u) && nd[v] > best) { best = nd[v]; bi = v; }
            }
            vals[j] = best; ids[j] = bi; taken |= (1u << bi);
        }
        float m = vals[0], se = 0.f, e[TOPK_];
        #pragma unroll
        for (int j = 0; j < TOPK_; ++j) { e[j] = expf(vals[j] - m); se += e[j]; }
        float invse = 1.f / se;
        float* row = inc + u * VT_;
        #pragma unroll
        for (int v = 0; v < VT_; ++v) row[v] = 0.f;
        for (int j = 0; j < TOPK_; ++j) row[ids[j]] = e[j] * invse;
    } else if (tid >= 64 && tid < 64 + VT_) {
        int v = tid - 64;
        float s = to_w2_b[k];
        #pragma unroll
        for (int q = 0; q < K_ * H_; ++q)
            s += w1s[q * VT_ + v] * to_w2_w[k * K_ * H_ + q];
        wt30[v] = tanhf(s);
    } else if (tid >= 128 && tid < 128 + VT_) {
        int u = tid - 128;
        float sa = 0.f;
        const float* ea = edge + (size_t)(k * VT_ + u) * VT_;
        const float* aa = adjc + (size_t)(k * VT_ + u) * VT_;
        #pragma unroll
        for (int w2 = 0; w2 < VT_; ++w2) sa += fabsf(ea[w2] * aa[w2]);
        rsA30[u] = sa + 1e-8f;
    }
    __syncthreads();

    // ---- gv (w0) and rs (w1) ----
    if (tid < VT_) {
        int v = tid;
        float cs = 0.f;
        #pragma unroll
        for (int u = 0; u < VT_; ++u) cs += fabsf(inc[u * VT_ + v]);
        float d = wt30[v] / (cs + 1e-8f);
        gv30[v] = wt30[v] * d;
    } else if (tid >= 64 && tid < 64 + VT_) {
        int u = tid - 64;
        float s = 0.f;
        const float* row = inc + u * VT_;
        #pragma unroll
        for (int vv = 0; vv < VT_; ++vv) s += fabsf(row[vv] * wt30[vv]);
        rs30[u] = s + 1e-8f;
    }
    __syncthreads();

    // ---- adjR[u][v] for own k: 1024 outputs, 4 per thread ----
    float ar = alpha[0]; ar = ar > 0.f ? ar : 0.f;
    size_t obase = (size_t)b * 1024;
    #pragma unroll
    for (int ii = 0; ii < 4; ++ii) {
        int i = tid + ii * 256;
        int u = i >> 5, v = i & 31;
        float val = 0.f;
        if (u < VT_ && v < VT_) {
            const float* ru = inc + u * VT_;
            const float* rw = inc + v * VT_;
            float s = 0.f;
            #pragma unroll
            for (int vv = 0; vv < VT_; ++vv) s += ru[vv] * gv30[vv] * rw[vv];
            float inv_rs = 1.0f / rs30[u];
            float inv_rsA = 1.0f / rsA30[u];
            int ei = (k * VT_ + u) * VT_ + v;
            val = edge[ei] * adjc[ei] * inv_rsA + ar * (s * inv_rs);
        }
        adjR[obase + i] = val;
    }
}

// ---------------- Kernel 3: 8-t tile (grid halved), row-contiguous LDS ------
// Block (n,k,tc): stage x[32c][8t*25v] -> xs[c][204] (200 used) as pure f32x4
// copies (204 mod 32 = 12, gcd 4 -> <=2-way bank aliasing = free).
// Wave w sequentially handles tl = w and w+4 (Mb reused; same-wave ds order).
// Per tl: GEMM-M -> Mb packed bf16 -> GEMM-Y -> in-place epilogue at
// xs[c][tl*25+u] (disjoint windows). Barrier + f32x4 nt writeback.
// 8t/block halves per-t share of block-constant loads, barriers, launches.
__global__ __launch_bounds__(256, 4) void k_main(
    const float* __restrict__ x, const float* __restrict__ hyper,
    const float* __restrict__ adjR,
    const float* __restrict__ conv_w, const float* __restrict__ conv_b,
    const float* __restrict__ gamma, const float* __restrict__ beta,
    float* __restrict__ out) {
    __shared__ __align__(16) float xs[32 * 204];        // [c][204], 200 used
    __shared__ __align__(16) unsigned Mb[4 * 32 * 18];  // per-wave [u][18]

    int b = blockIdx.x;
    int tc = b & 7, k = (b >> 3) & 7, n = b >> 6;
    int tid = threadIdx.x;
    int w = tid >> 6;
    int lane = tid & 63;
    int qd = lane >> 4;        // quad 0..3
    int l16 = lane & 15;

    // ---- stage x slice (32c x 200 floats) coalesced: 1600 f32x4 copies ----
    const float* xg = x + ((size_t)(n * C_ + k * CG_) * T_ + tc * 8) * V_;
    #pragma unroll
    for (int ii = 0; ii < 7; ++ii) {
        int i = tid + ii * 256;
        if (i < 1600) {
            int c = i / 50, col = i % 50;
            f32x4 f4 = *(const f32x4*)(xg + (size_t)c * (T_ * V_) + col * 4);
            *(f32x4*)(xs + c * 204 + col * 4) = f4;
        }
    }

    // ---- block-constant register fragments (issued while staging in flight) --
    short8 Wf[2];   // W[o=16mi+l16][c=qd*8+j]
    #pragma unroll
    for (int mi = 0; mi < 2; ++mi) {
        const float* wp = conv_w + (size_t)(k * OG_ + 16 * mi + l16) * CG_ + qd * 8;
        Wf[mi] = mk8(*(const f32x4*)wp, *(const f32x4*)(wp + 4));
    }
    short8 Bf[2]; float Su[2];   // adjR[u=16ni+l16][v=qd*8+j]; f32 row sums S[u]
    #pragma unroll
    for (int ni = 0; ni < 2; ++ni) {
        const float* ap = adjR + (((size_t)(n * K_ + k)) * 32 + 16 * ni + l16) * 32 + qd * 8;
        f32x4 a0 = *(const f32x4*)ap, a1 = *(const f32x4*)(ap + 4);
        Bf[ni] = mk8(a0, a1);
        float s = a0[0] + a0[1] + a0[2] + a0[3] + a1[0] + a1[1] + a1[2] + a1[3];
        s += __shfl_xor(s, 16);
        s += __shfl_xor(s, 32);
        Su[ni] = s;
    }
    f32x4 cb4[2], sc4[2], bt4[2];   // per o-quad: o = 16mi + qd*4 + r
    #pragma unroll
    for (int mi = 0; mi < 2; ++mi) {
        int o0 = k * OG_ + 16 * mi + qd * 4;
        cb4[mi] = *(const f32x4*)(conv_b + o0);
        f32x4 g = *(const f32x4*)(gamma + o0);
        #pragma unroll
        for (int r = 0; r < 4; ++r) g[r] *= 0.999995000037f;  // 1/sqrt(1+1e-5)
        sc4[mi] = g;
        bt4[mi] = *(const f32x4*)(beta + o0);
    }
    short8 Ht[2];   // qd==3 A-template: slot0=x[..][24] (per t), 1..5=hyper, 6,7=0
    #pragma unroll
    for (int mi = 0; mi < 2; ++mi) {
        int c = k * CG_ + 16 * mi + l16;
        short8 h;
        h[0] = 0; h[6] = 0; h[7] = 0;
        #pragma unroll
        for (int j = 0; j < 5; ++j) h[1 + j] = bfbits(hyper[j * C_ + c]);
        Ht[mi] = h;
    }

    __syncthreads();

    unsigned* Mbw = Mb + w * (32 * 18);

    #pragma unroll
    for (int tt = 0; tt < 2; ++tt) {
        int tl = w + 4 * tt;   // wave w owns t-windows w and w+4

        // A-frags: xv[c=16mi+l16][v=qd*8+j] at xs[c*204 + tl*25 + v]
        short8 Ax[2];
        #pragma unroll
        for (int mi = 0; mi < 2; ++mi) {
            const float* xp = xs + (16 * mi + l16) * 204 + tl * 25;
            if (qd < 3) {
                float va[8];
                #pragma unroll
                for (int j = 0; j < 8; ++j) va[j] = xp[qd * 8 + j];
                Ax[mi] = mk8f(va);
            } else {
                short8 h = Ht[mi];
                h[0] = bfbits(xp[24]);
                Ax[mi] = h;
            }
        }
        // GEMM-M: lane(qd,l16) gets M[c=16mi+qd*4+r][u=16ni+l16]
        f32x4 CM[2][2];
        #pragma unroll
        for (int mi = 0; mi < 2; ++mi)
            #pragma unroll
            for (int ni = 0; ni < 2; ++ni) {
                f32x4 z = {0.f, 0.f, 0.f, 0.f};
                CM[mi][ni] = __builtin_amdgcn_mfma_f32_16x16x32_bf16(Ax[mi], Bf[ni], z, 0, 0, 0);
            }
        // M -> Mb packed bf16: row u, dword d = 8mi + 2qd + {0,1} holds c {2d,2d+1}
        #pragma unroll
        for (int mi = 0; mi < 2; ++mi)
            #pragma unroll
            for (int ni = 0; ni < 2; ++ni) {
                int u = 16 * ni + l16;
                uint2 pr;
                pr.x = pkbf(CM[mi][ni][0], CM[mi][ni][1]);
                pr.y = pkbf(CM[mi][ni][2], CM[mi][ni][3]);
                *(uint2*)(Mbw + u * 18 + 8 * mi + 2 * qd) = pr;
            }
        // B-frags of GEMM-Y: M[u=16ni+l16][c=qd*8+j] -> dwords qd*4..qd*4+3
        short8 Bm[2];
        #pragma unroll
        for (int ni = 0; ni < 2; ++ni) {
            int u = 16 * ni + l16;
            uint2 lo = *(const uint2*)(Mbw + u * 18 + qd * 4);
            uint2 hi = *(const uint2*)(Mbw + u * 18 + qd * 4 + 2);
            union { unsigned uu[4]; short8 s; } bm;
            bm.uu[0] = lo.x; bm.uu[1] = lo.y; bm.uu[2] = hi.x; bm.uu[3] = hi.y;
            Bm[ni] = bm.s;
        }
        // GEMM-Y
        f32x4 CY[2][2];
        #pragma unroll
        for (int mi = 0; mi < 2; ++mi)
            #pragma unroll
            for (int ni = 0; ni < 2; ++ni) {
                f32x4 z = {0.f, 0.f, 0.f, 0.f};
                CY[mi][ni] = __builtin_amdgcn_mfma_f32_16x16x32_bf16(Wf[mi], Bm[ni], z, 0, 0, 0);
            }
        // epilogue in place: res at xs[c=16mi+qd*4+r][tl*25 + u]
        #pragma unroll
        for (int ni = 0; ni < 2; ++ni) {
            int u = 16 * ni + l16;
            if (u < V_) {
                #pragma unroll
                for (int mi = 0; mi < 2; ++mi) {
                    #pragma unroll
                    for (int r = 0; r < 4; ++r) {
                        float* rp = xs + (16 * mi + qd * 4 + r) * 204 + tl * 25 + u;
                        float res = *rp;
                        float val = (CY[mi][ni][r] + cb4[mi][r] * Su[ni]) * sc4[mi][r]
                                    + bt4[mi][r] + res;
                        *rp = val > 0.f ? val : 0.f;
                    }
                }
            }
        }
    }

    __syncthreads();

    // ---- coalesced nontemporal writeback (exact inverse of staging) ----
    float* og = out + ((size_t)(n * C_ + k * CG_) * T_ + tc * 8) * V_;
    #pragma unroll
    for (int ii = 0; ii < 7; ++ii) {
        int i = tid + ii * 256;
        if (i < 1600) {
            int c = i / 50, col = i % 50;
            f32x4 f4 = *(const f32x4*)(xs + c * 204 + col * 4);
            __builtin_nontemporal_store(f4, (f32x4*)(og + (size_t)c * (T_ * V_) + col * 4));
        }
    }
}

extern "C" void kernel_launch(void* const* d_in, const int* in_sizes, int n_in,
                              void* d_out, int out_size, void* d_ws, size_t ws_size,
                              hipStream_t stream) {
    const float* x     = (const float*)d_in[0];
    const float* adjc  = (const float*)d_in[1];
    const float* edge  = (const float*)d_in[2];
    const float* hyper = (const float*)d_in[3];
    const float* alpha = (const float*)d_in[4];
    const float* tvw   = (const float*)d_in[5];
    const float* tvb   = (const float*)d_in[6];
    const float* t1w   = (const float*)d_in[7];
    const float* t1b   = (const float*)d_in[8];
    const float* t2w   = (const float*)d_in[9];
    const float* t2b   = (const float*)d_in[10];
    const float* cw    = (const float*)d_in[11];
    const float* cb    = (const float*)d_in[12];
    const float* gam   = (const float*)d_in[13];
    const float* bet   = (const float*)d_in[14];
    float* out = (float*)d_out;

    float* pooled = (float*)d_ws;                    // N*C*25 fp32
    float* adjR   = pooled + N_ * C_ * V_;           // N*K*32*32 fp32

    k_pool<<<dim3(N_ * 64 + 1), dim3(256), 0, stream>>>(
        x, hyper, pooled, out + (size_t)N_ * O_ * T_ * V_);
    k_graph<<<dim3(N_ * K_), dim3(256), 0, stream>>>(
        pooled, hyper, adjc, edge, alpha, tvw, tvb, t1w, t1b, t2w, t2b, adjR);
    k_main<<<dim3(N_ * K_ * 8), dim3(256), 0, stream>>>(
        x, hyper, adjR, cw, cb, gam, bet, out);
}